// Round 14
// baseline (183.852 us; speedup 1.0000x reference)
//
#include <hip/hip_runtime.h>
#include <math.h>

#define B_ 128
#define E_ 512
#define C_ 128
#define H_ 8
#define D_ 64
#define BEC_ ((size_t)B_ * E_ * C_)

typedef __attribute__((ext_vector_type(8))) __bf16 bf16x8;
typedef __attribute__((ext_vector_type(4))) float f32x4;

__device__ __forceinline__ ushort f2bf(float f) {
    unsigned u = __float_as_uint(f);
    unsigned r = u + 0x7fffu + ((u >> 16) & 1u);
    return (ushort)(r >> 16);
}
__device__ __forceinline__ float bf2f(ushort h) {
    return __uint_as_float(((unsigned)h) << 16);
}
__device__ __forceinline__ void split_bf(float f, ushort& hi, ushort& lo) {
    hi = f2bf(f);
    lo = f2bf(f - bf2f(hi));
}
__device__ __forceinline__ float selu_f(float x) {
    const float alpha = 1.6732632423543772f;
    const float scale = 1.0507009873554805f;
    return x > 0.0f ? scale * x : scale * alpha * expm1f(x);
}
// async global->LDS, 16B/lane; LDS dest wave-uniform base + lane*16
__device__ __forceinline__ void gll16(const void* g, void* l) {
    __builtin_amdgcn_global_load_lds(
        (const __attribute__((address_space(1))) void*)g,
        (__attribute__((address_space(3))) void*)l, 16, 0, 0);
}

// ---------------------------------------------------------------------------
// combT[h][j][i] = mask(i,j) ? attn_bias[i][j] + centered dir bias(i,j) : -inf
// Mask dtype detect inlined (first 2048 bytes: bool -> 336 nonzero, int -> 84).
// ---------------------------------------------------------------------------
__global__ __launch_bounds__(128) void bias_prep_kernel(
    const float* __restrict__ dir_vec, const float* __restrict__ attn_bias,
    const float* __restrict__ disp, const unsigned char* __restrict__ maskb,
    float* __restrict__ combT)
{
    const int i = blockIdx.x, h = blockIdx.y, j = threadIdx.x;
    __shared__ float red[128];
    __shared__ int boolFlag;

    {   // inline dtype sniff
        int cnt = 0;
        const int base = j * 16;
#pragma unroll
        for (int t = 0; t < 16; ++t) cnt += (maskb[base + t] != 0);
        red[j] = (float)cnt;
        __syncthreads();
        for (int s = 64; s > 0; s >>= 1) {
            if (j < s) red[j] += red[j + s];
            __syncthreads();
        }
        if (j == 0) boolFlag = (red[0] > 200.0f) ? 1 : 0;
        __syncthreads();
    }

    float dv = dir_vec[h * C_ + j];
    red[j] = dv * dv;
    __syncthreads();
    for (int s = 64; s > 0; s >>= 1) {
        if (j < s) red[j] += red[j + s];
        __syncthreads();
    }
    const float nrm = fmaxf(sqrtf(red[0]), 1e-12f);
    __syncthreads();

    const float dvn_j = dir_vec[h * C_ + j] / nrm;
    const float dvn_i = dir_vec[h * C_ + i] / nrm;
    const float third = 1.0f / 3.0f;
    const float dm_ij = (disp[(i * C_ + j) * 3 + 0] + disp[(i * C_ + j) * 3 + 1] +
                         disp[(i * C_ + j) * 3 + 2]) * third;
    const float dm_ji = (disp[(j * C_ + i) * 3 + 0] + disp[(j * C_ + i) * 3 + 1] +
                         disp[(j * C_ + i) * 3 + 2]) * third;
    const float db = 0.5f * (dm_ij * dvn_j - dm_ji * dvn_i);

    red[j] = db;
    __syncthreads();
    for (int s = 64; s > 0; s >>= 1) {
        if (j < s) red[j] += red[j + s];
        __syncthreads();
    }
    const float rowmean = red[0] * (1.0f / 128.0f);

    const bool mk = boolFlag ? (maskb[i * C_ + j] != 0)
                             : (((const int*)maskb)[i * C_ + j] != 0);
    combT[((size_t)h * C_ + j) * C_ + i] =
        mk ? (attn_bias[i * C_ + j] + db - rowmean) : -INFINITY;
}

// ---------------------------------------------------------------------------
// Fused weight + x split (verbatim round-11/13, passing).
// ---------------------------------------------------------------------------
__global__ __launch_bounds__(256) void split_kernel(
    const float* __restrict__ w0, const float* __restrict__ w1,
    const float* __restrict__ w2, const float* __restrict__ w3,
    const float* __restrict__ x,
    ushort* __restrict__ wh, ushort* __restrict__ wl,
    ushort* __restrict__ xh, ushort* __restrict__ xl)
{
    __shared__ float ts[64][132];
    const int id = blockIdx.x;
    const int tid = threadIdx.x;

    if (id < 512) {
        const int s = id >> 7;
        const float* __restrict__ w = (s == 0) ? w0 : (s == 1) ? w1
                                    : (s == 2) ? w2 : w3;
        const size_t base = (size_t)s * E_ * E_;
        const size_t i0 = ((size_t)(id & 127) * 256 + tid) * 8;
        const float4 f0 = *(const float4*)&w[i0];
        const float4 f1 = *(const float4*)&w[i0 + 4];
        const float ff[8] = {f0.x, f0.y, f0.z, f0.w, f1.x, f1.y, f1.z, f1.w};
        union { ushort u[8]; uint4 v; } hu, lu;
#pragma unroll
        for (int j = 0; j < 8; ++j) split_bf(ff[j], hu.u[j], lu.u[j]);
        *(uint4*)&wh[base + i0] = hu.v;
        *(uint4*)&wl[base + i0] = lu.v;
        return;
    }

    const int fid = id - 512;
    const int b = fid >> 3, e0 = (fid & 7) * 64;
    const float* __restrict__ xb = x + ((size_t)b * E_ + e0) * C_;
#pragma unroll
    for (int r = 0; r < 8; ++r) {
        const int idx = tid + r * 256;
        const int e = idx >> 5, c4 = idx & 31;
        *(float4*)&ts[e][c4 * 4] = *(const float4*)&xb[(size_t)e * C_ + c4 * 4];
    }
    __syncthreads();
    const int lc = tid >> 3;
    const int l8 = (tid & 7) * 8;
#pragma unroll
    for (int p = 0; p < 4; ++p) {
        const int c = p * 32 + lc;
        union { ushort u[8]; uint4 v; } hu, lu;
#pragma unroll
        for (int j = 0; j < 8; ++j) split_bf(ts[l8 + j][c], hu.u[j], lu.u[j]);
        const size_t rb = ((size_t)b * C_ + c) * E_ + e0 + l8;
        *(uint4*)&xh[rb] = hu.v;
        *(uint4*)&xl[rb] = lu.v;
    }
}

// ---------------------------------------------------------------------------
// Split-bf16 MFMA GEMM, T3-minimum prefetch variant.
// Identical work/tiles to r13 (128x128 block, 4 waves, 3-term split, b-grouped
// XCD remap, 64KB LDS, 2 blocks/CU) — ONLY the K-loop ordering changes:
// BK=32 with TWO 32KB buffers; each iteration issues STAGE(t+1) into the idle
// buffer BEFORE frag-reads+MFMA on buffer t, so __syncthreads' vmcnt(0) drain
// happens ~1300cy after load issue (L2-hot loads complete -> drain free).
// Race-free: a buffer is staged only after the barrier ending its reads.
// 64B-row swizzle = r8-proven pair (0 conflicts): src chunk
// (lane&3)^((lane>>3)&3); read koff ((lane>>4)^((l15>>1)&3))<<4.
// MODE 0: z=0 q trans split / z=1 k trans split / z=2 v natural hi-only
// (2-term, wave1 stages nothing). MODE 1: out-proj fp32+selu (3-term).
// ---------------------------------------------------------------------------
template<int MODE>
__global__ __launch_bounds__(256, 2) void gemm_kernel(
    const ushort* __restrict__ Wh0, const ushort* __restrict__ Wh1,
    const ushort* __restrict__ Wh2, const ushort* __restrict__ Wl0,
    const ushort* __restrict__ Wl1, const ushort* __restrict__ Wl2,
    const ushort* __restrict__ Bh, const ushort* __restrict__ Bl,
    ushort* __restrict__ qh, ushort* __restrict__ ql,
    ushort* __restrict__ kh, ushort* __restrict__ kl,
    ushort* __restrict__ vhp, float* __restrict__ fout)
{
    // b-grouped XCD remap
    const int d = blockIdx.x;
    const int xr = d & 7, slot = d >> 3;
    const int G = (MODE == 0) ? 12 : 4;
    const int b = xr + 8 * (slot / G);
    const int u = slot % G;
    const int z = (MODE == 0) ? (u >> 2) : 0;
    const int o0 = (MODE == 0) ? ((u & 3) * 128) : (u * 128);

    const ushort* __restrict__ wh = (z == 0) ? Wh0 : (z == 1) ? Wh1 : Wh2;
    const ushort* __restrict__ wl = (z == 0) ? Wl0 : (z == 1) ? Wl1 : Wl2;
    const bool trans = (MODE == 0) && (z < 2);
    const bool full3 = (MODE == 1) || (z != 2);   // v: 2-term split

    // 2 buffers x {Wh 8K | Wl 8K | Xh 8K | Xl 8K} bytes = 64 KB total
    __shared__ ushort sm[2 * 16384];

    const int tid = threadIdx.x;
    const int wid = tid >> 6, lane = tid & 63;
    const int wr64 = (wid >> 1) * 64, wc64 = (wid & 1) * 64;
    const int l15 = lane & 15;

    const char* __restrict__ bhp = (const char*)(Bh + (size_t)b * C_ * E_);
    const char* __restrict__ blp = (const char*)(Bl + (size_t)b * C_ * E_);

    // ---- staging: wave `wid` owns plane wid (Wh/Wl/Xh/Xl); 8 insts x 16 rows
    const char* __restrict__ sptr =
        (wid == 0) ? (const char*)wh : (wid == 1) ? (const char*)wl
      : (wid == 2) ? bhp : blp;
    const int rowbase = (wid < 2) ? o0 : 0;
    const unsigned chunkSwz = (unsigned)(((lane & 3) ^ ((lane >> 3) & 3)) * 16);
    unsigned sgo[8];
#pragma unroll
    for (int inst = 0; inst < 8; ++inst)
        sgo[inst] = (unsigned)((rowbase + inst * 16 + (lane >> 2)) * (E_ * 2)) +
                    chunkSwz;
    const bool doStage = full3 || (wid != 1);

    // ---- frag read byte offsets within a 32KB buffer (swizzled k-slot)
    const int koff = ((lane >> 4) ^ ((l15 >> 1) & 3)) << 4;
    const int aPl = trans ? 16384 : 0;   // A hi plane base (lo at +8192)
    const int bPl = trans ? 0 : 16384;
    int aoffs[4], boffs[4];
#pragma unroll
    for (int m = 0; m < 4; ++m)
        aoffs[m] = aPl + (wr64 + m * 16 + l15) * 64 + koff;
#pragma unroll
    for (int n = 0; n < 4; ++n)
        boffs[n] = bPl + (wc64 + n * 16 + l15) * 64 + koff;

    f32x4 acc[4][4];
#pragma unroll
    for (int m = 0; m < 4; ++m)
#pragma unroll
        for (int n = 0; n < 4; ++n) acc[m][n] = (f32x4)0.0f;

    // ---- prologue: stage K-tile 0 into buf0
    if (doStage) {
#pragma unroll
        for (int inst = 0; inst < 8; ++inst)
            gll16(sptr + sgo[inst], &sm[wid * 4096 + inst * 512]);
    }
    __syncthreads();

    for (int t = 0; t < 16; ++t) {
        const char* __restrict__ bb = (const char*)sm + (t & 1) * 32768;

        // issue next-tile stage into the idle buffer BEFORE compute
        if (t < 15 && doStage) {
            ushort* nb = sm + ((t + 1) & 1) * 16384;
            const unsigned kadd = (unsigned)(t + 1) * 64;
#pragma unroll
            for (int inst = 0; inst < 8; ++inst)
                gll16(sptr + sgo[inst] + kadd, &nb[wid * 4096 + inst * 512]);
        }

        // frag reads + MFMA on current buffer (compiler inserts lgkmcnt)
        bf16x8 ah[4], al[4], bh4[4], bl4[4];
#pragma unroll
        for (int m = 0; m < 4; ++m) {
            ah[m] = *(const bf16x8*)(bb + aoffs[m]);
            if (full3) al[m] = *(const bf16x8*)(bb + aoffs[m] + 8192);
        }
#pragma unroll
        for (int n = 0; n < 4; ++n) {
            bh4[n] = *(const bf16x8*)(bb + boffs[n]);
            bl4[n] = *(const bf16x8*)(bb + boffs[n] + 8192);
        }
#pragma unroll
        for (int m = 0; m < 4; ++m)
#pragma unroll
            for (int n = 0; n < 4; ++n)
                acc[m][n] = __builtin_amdgcn_mfma_f32_16x16x32_bf16(
                    ah[m], bh4[n], acc[m][n], 0, 0, 0);
#pragma unroll
        for (int m = 0; m < 4; ++m)
#pragma unroll
            for (int n = 0; n < 4; ++n)
                acc[m][n] = __builtin_amdgcn_mfma_f32_16x16x32_bf16(
                    ah[m], bl4[n], acc[m][n], 0, 0, 0);
        if (full3) {
#pragma unroll
            for (int m = 0; m < 4; ++m)
#pragma unroll
                for (int n = 0; n < 4; ++n)
                    acc[m][n] = __builtin_amdgcn_mfma_f32_16x16x32_bf16(
                        al[m], bh4[n], acc[m][n], 0, 0, 0);
        }

        __syncthreads();   // drains vmcnt(0)+lgkm; next tile ready, buffer freed
    }

    const int lr = (lane >> 4) * 4, lc = lane & 15;   // C/D: col=lane&15
    if (MODE == 1) {
        float* __restrict__ outb = fout + (size_t)b * E_ * C_;
#pragma unroll
        for (int m = 0; m < 4; ++m)
#pragma unroll
            for (int n = 0; n < 4; ++n) {
                float* po = outb + (size_t)(o0 + wr64 + m * 16 + lr) * C_ +
                            wc64 + n * 16 + lc;
                const f32x4 a = acc[m][n];
#pragma unroll
                for (int j = 0; j < 4; ++j) po[(size_t)j * C_] = selu_f(a[j]);
            }
    } else if (z == 2) {
        // v: natural [b][E][C], hi only
#pragma unroll
        for (int m = 0; m < 4; ++m)
#pragma unroll
            for (int n = 0; n < 4; ++n) {
                const f32x4 a = acc[m][n];
#pragma unroll
                for (int j = 0; j < 4; ++j) {
                    const size_t idx = ((size_t)b * E_ + o0 + wr64 + m * 16 + lr + j) * C_ +
                                       wc64 + n * 16 + lc;
                    vhp[idx] = f2bf(selu_f(a[j]));
                }
            }
    } else {
        // q/k: transposed [b][c][E], split hi/lo. rows=c, cols=o.
        ushort* __restrict__ th = z ? kh : qh;
        ushort* __restrict__ tl = z ? kl : ql;
#pragma unroll
        for (int m = 0; m < 4; ++m)
#pragma unroll
            for (int n = 0; n < 4; ++n) {
                const f32x4 a = acc[m][n];
#pragma unroll
                for (int j = 0; j < 4; ++j) {
                    const int c = wr64 + m * 16 + lr + j;
                    const int o = o0 + wc64 + n * 16 + lc;
                    const size_t idx = ((size_t)b * C_ + c) * E_ + o;
                    ushort hi, lo;
                    split_bf(selu_f(a[j]), hi, lo);
                    th[idx] = hi;
                    tl[idx] = lo;
                }
            }
    }
}

// ---------------------------------------------------------------------------
// MFMA attention, one block (4 waves) per (b,h), b-grouped XCD remap.
// 80 KB LDS -> 2 blocks/CU. (verbatim r11/r13, verified passing)
// ---------------------------------------------------------------------------
__global__ __launch_bounds__(256, 2) void attn_mfma_kernel(
    const ushort* __restrict__ qTh, const ushort* __restrict__ qTl,
    const ushort* __restrict__ kTh, const ushort* __restrict__ kTl,
    const ushort* __restrict__ vh,  const float* __restrict__ combT,
    ushort* __restrict__ aTh, ushort* __restrict__ aTl)
{
    const int dd_ = blockIdx.x;
    const int b = (dd_ & 7) + 8 * ((dd_ >> 3) >> 3);
    const int h = (dd_ >> 3) & 7;
    __shared__ ushort lds[40960];
    ushort* sQh = lds;
    ushort* sQl = lds + 8192;
    ushort* sKh = lds + 16384;
    ushort* sKl = lds + 24576;
    ushort* sV  = lds + 32768;
    ushort* sPh = lds;
    ushort* sPl = lds + 16384;

    const int tid = threadIdx.x, wid = tid >> 6, lane = tid & 63;

    {
        const size_t gq = (size_t)b * C_ * E_ + h * D_;
        const int rsub = lane >> 3, chunk = lane & 7;
#pragma unroll
        for (int t = 0; t < 4; ++t) {
            const int inst = wid * 4 + t;
            const int row = inst * 8 + rsub;
            const size_t goff = (gq + (size_t)row * E_) * 2 +
                                (size_t)(chunk ^ (row & 7)) * 16;
            gll16((const char*)qTh + goff, &sQh[inst * 512]);
            gll16((const char*)qTl + goff, &sQl[inst * 512]);
            gll16((const char*)kTh + goff, &sKh[inst * 512]);
            gll16((const char*)kTl + goff, &sKl[inst * 512]);
        }
        const size_t gv = ((size_t)b * E_ + h * D_) * C_;
        const int vr = lane >> 4, vchunk = lane & 15;
#pragma unroll
        for (int t = 0; t < 4; ++t) {
            const int inst = wid * 4 + t;
            const int row = inst * 4 + vr;
            const size_t goff = (gv + (size_t)row * C_) * 2 +
                                (size_t)(vchunk ^ (row & 7)) * 16;
            gll16((const char*)vh + goff, &sV[inst * 512]);
        }
    }
    __syncthreads();

    const int i0 = wid * 32;
    const int l15 = lane & 15;

    f32x4 acc[2][8];
#pragma unroll
    for (int m = 0; m < 2; ++m)
#pragma unroll
        for (int n = 0; n < 8; ++n) acc[m][n] = (f32x4)0.0f;

#pragma unroll
    for (int kk = 0; kk < 2; ++kk) {
        const int kbyte = kk * 64 + (lane >> 4) * 16;
        bf16x8 qhf[2], qlf[2];
#pragma unroll
        for (int m = 0; m < 2; ++m) {
            const int r = i0 + m * 16 + l15;
            const int byt = r * 128 + (kbyte ^ ((r & 7) << 4));
            qhf[m] = *(const bf16x8*)((const char*)sQh + byt);
            qlf[m] = *(const bf16x8*)((const char*)sQl + byt);
        }
#pragma unroll
        for (int n = 0; n < 8; ++n) {
            const int r = n * 16 + l15;
            const int byt = r * 128 + (kbyte ^ ((r & 7) << 4));
            const bf16x8 khf = *(const bf16x8*)((const char*)sKh + byt);
            const bf16x8 klf = *(const bf16x8*)((const char*)sKl + byt);
#pragma unroll
            for (int m = 0; m < 2; ++m) {
                acc[m][n] = __builtin_amdgcn_mfma_f32_16x16x32_bf16(
                    qhf[m], khf, acc[m][n], 0, 0, 0);
                acc[m][n] = __builtin_amdgcn_mfma_f32_16x16x32_bf16(
                    qhf[m], klf, acc[m][n], 0, 0, 0);
                acc[m][n] = __builtin_amdgcn_mfma_f32_16x16x32_bf16(
                    qlf[m], khf, acc[m][n], 0, 0, 0);
            }
        }
    }

#pragma unroll
    for (int m = 0; m < 2; ++m)
#pragma unroll
        for (int n = 0; n < 8; ++n) {
            const int jcol = n * 16 + l15;
            const float4 cb = *(const float4*)&combT[
                ((size_t)h * C_ + jcol) * C_ + i0 + m * 16 + (lane >> 4) * 4];
            acc[m][n][0] = fmaf(acc[m][n][0], 0.125f, cb.x);
            acc[m][n][1] = fmaf(acc[m][n][1], 0.125f, cb.y);
            acc[m][n][2] = fmaf(acc[m][n][2], 0.125f, cb.z);
            acc[m][n][3] = fmaf(acc[m][n][3], 0.125f, cb.w);
        }

#pragma unroll
    for (int m = 0; m < 2; ++m)
#pragma unroll
        for (int jj = 0; jj < 4; ++jj) {
            float mx = -INFINITY;
#pragma unroll
            for (int n = 0; n < 8; ++n) mx = fmaxf(mx, acc[m][n][jj]);
#pragma unroll
            for (int off = 1; off < 16; off <<= 1)
                mx = fmaxf(mx, __shfl_xor(mx, off));
            float sum = 0.0f;
#pragma unroll
            for (int n = 0; n < 8; ++n) {
                const float e = __expf(acc[m][n][jj] - mx);
                acc[m][n][jj] = e;
                sum += e;
            }
#pragma unroll
            for (int off = 1; off < 16; off <<= 1) sum += __shfl_xor(sum, off);
            const float inv = 1.0f / sum;
#pragma unroll
            for (int n = 0; n < 8; ++n) acc[m][n][jj] *= inv;
        }

    __syncthreads();
#pragma unroll
    for (int m = 0; m < 2; ++m)
#pragma unroll
        for (int n = 0; n < 8; ++n)
#pragma unroll
            for (int jj = 0; jj < 4; ++jj) {
                const int i = i0 + m * 16 + (lane >> 4) * 4 + jj;
                const int col = n * 16 + l15;
                const int byt = i * 256 + ((col * 2) ^ ((i & 7) << 4));
                ushort hi, lo;
                split_bf(acc[m][n][jj], hi, lo);
                *(ushort*)((char*)sPh + byt) = hi;
                *(ushort*)((char*)sPl + byt) = lo;
            }
    __syncthreads();

    f32x4 acc2[2][4];
#pragma unroll
    for (int m = 0; m < 2; ++m)
#pragma unroll
        for (int n = 0; n < 4; ++n) acc2[m][n] = (f32x4)0.0f;

#pragma unroll
    for (int ks = 0; ks < 4; ++ks) {
        const int kbyte = ks * 64 + (lane >> 4) * 16;
        bf16x8 ph[2], pl[2];
#pragma unroll
        for (int m = 0; m < 2; ++m) {
            const int r = i0 + m * 16 + l15;
            const int byt = r * 256 + (kbyte ^ ((r & 7) << 4));
            ph[m] = *(const bf16x8*)((const char*)sPh + byt);
            pl[m] = *(const bf16x8*)((const char*)sPl + byt);
        }
#pragma unroll
        for (int n = 0; n < 4; ++n) {
            const int dcol = n * 16 + l15;
            const int byt = dcol * 256 + (kbyte ^ ((dcol & 7) << 4));
            const bf16x8 vb = *(const bf16x8*)((const char*)sV + byt);
#pragma unroll
            for (int m = 0; m < 2; ++m) {
                acc2[m][n] = __builtin_amdgcn_mfma_f32_16x16x32_bf16(
                    ph[m], vb, acc2[m][n], 0, 0, 0);
                acc2[m][n] = __builtin_amdgcn_mfma_f32_16x16x32_bf16(
                    pl[m], vb, acc2[m][n], 0, 0, 0);
            }
        }
    }

#pragma unroll
    for (int m = 0; m < 2; ++m)
#pragma unroll
        for (int n = 0; n < 4; ++n)
#pragma unroll
            for (int jj = 0; jj < 4; ++jj) {
                const int i = i0 + m * 16 + (lane >> 4) * 4 + jj;
                const int dcol = n * 16 + l15;
                ushort hi, lo;
                split_bf(acc2[m][n][jj], hi, lo);
                const size_t idx = ((size_t)b * C_ + i) * E_ + h * D_ + dcol;
                aTh[idx] = hi;
                aTl[idx] = lo;
            }
}

// ---------------------------------------------------------------------------
extern "C" void kernel_launch(void* const* d_in, const int* in_sizes, int n_in,
                              void* d_out, int out_size, void* d_ws, size_t ws_size,
                              hipStream_t stream) {
    const float* x        = (const float*)d_in[0];
    const float* wq       = (const float*)d_in[1];
    const float* wk       = (const float*)d_in[2];
    const float* wv       = (const float*)d_in[3];
    const float* wo       = (const float*)d_in[4];
    const float* dir_vec  = (const float*)d_in[5];
    const float* attn_b   = (const float*)d_in[6];
    const float* disp     = (const float*)d_in[7];
    const unsigned char* knn = (const unsigned char*)d_in[8];
    float* out = (float*)d_out;

    char* ws = (char*)d_ws;
    size_t off = 0;
    ushort* qTh = (ushort*)(ws + off); off += BEC_ * 2;
    ushort* qTl = (ushort*)(ws + off); off += BEC_ * 2;
    ushort* kTh = (ushort*)(ws + off); off += BEC_ * 2;
    ushort* kTl = (ushort*)(ws + off); off += BEC_ * 2;
    ushort* vbuf = (ushort*)(ws + off); off += BEC_ * 2;
    ushort* xTh = (ushort*)(ws + off); off += BEC_ * 2;   // reused as attnT hi
    ushort* xTl = (ushort*)(ws + off); off += BEC_ * 2;   // reused as attnT lo
    ushort* wh  = (ushort*)(ws + off); off += (size_t)4 * E_ * E_ * 2;
    ushort* wl  = (ushort*)(ws + off); off += (size_t)4 * E_ * E_ * 2;
    float* combT = (float*)(ws + off); off += (size_t)H_ * C_ * C_ * sizeof(float);

    // bias (with inline mask-dtype detect)
    bias_prep_kernel<<<dim3(C_, H_), 128, 0, stream>>>(dir_vec, attn_b, disp,
                                                       knn, combT);
    // fused weight + x split
    split_kernel<<<1536, 256, 0, stream>>>(wq, wk, wv, wo, x, wh, wl, xTh, xTl);

    const size_t WSZ = (size_t)E_ * E_;
    // q (trans), k (trans), v (natural hi, 2-term), b-grouped flat grid
    gemm_kernel<0><<<1536, 256, 0, stream>>>(
        wh, wh + WSZ, wh + 2 * WSZ, wl, wl + WSZ, wl + 2 * WSZ,
        xTh, xTl, qTh, qTl, kTh, kTl, vbuf, nullptr);
    // MFMA attention -> attnT over xT buffers, b-grouped flat grid
    attn_mfma_kernel<<<1024, 256, 0, stream>>>(
        qTh, qTl, kTh, kTl, vbuf, combT, xTh, xTl);
    // output projection -> d_out, b-grouped flat grid
    gemm_kernel<1><<<512, 256, 0, stream>>>(
        wh + 3 * WSZ, wh + 3 * WSZ, wh + 3 * WSZ,
        wl + 3 * WSZ, wl + 3 * WSZ, wl + 3 * WSZ,
        xTh, xTl, nullptr, nullptr, nullptr, nullptr, nullptr, out);
}

// Round 15
// 176.012 us; speedup vs baseline: 1.0445x; 1.0445x over previous
//
#include <hip/hip_runtime.h>
#include <math.h>

#define B_ 128
#define E_ 512
#define C_ 128
#define H_ 8
#define D_ 64
#define BEC_ ((size_t)B_ * E_ * C_)

typedef __attribute__((ext_vector_type(8))) __bf16 bf16x8;
typedef __attribute__((ext_vector_type(4))) float f32x4;

__device__ __forceinline__ ushort f2bf(float f) {
    unsigned u = __float_as_uint(f);
    unsigned r = u + 0x7fffu + ((u >> 16) & 1u);
    return (ushort)(r >> 16);
}
__device__ __forceinline__ float bf2f(ushort h) {
    return __uint_as_float(((unsigned)h) << 16);
}
__device__ __forceinline__ void split_bf(float f, ushort& hi, ushort& lo) {
    hi = f2bf(f);
    lo = f2bf(f - bf2f(hi));
}
__device__ __forceinline__ float selu_f(float x) {
    const float alpha = 1.6732632423543772f;
    const float scale = 1.0507009873554805f;
    return x > 0.0f ? scale * x : scale * alpha * expm1f(x);
}
// async global->LDS, 16B/lane; LDS dest wave-uniform base + lane*16
__device__ __forceinline__ void gll16(const void* g, void* l) {
    __builtin_amdgcn_global_load_lds(
        (const __attribute__((address_space(1))) void*)g,
        (__attribute__((address_space(3))) void*)l, 16, 0, 0);
}

// ---------------------------------------------------------------------------
// combT[h][j][i] = mask(i,j) ? attn_bias[i][j] + centered dir bias(i,j) : -inf
// Mask dtype detect inlined (first 2048 bytes: bool -> 336 nonzero, int -> 84).
// ---------------------------------------------------------------------------
__global__ __launch_bounds__(128) void bias_prep_kernel(
    const float* __restrict__ dir_vec, const float* __restrict__ attn_bias,
    const float* __restrict__ disp, const unsigned char* __restrict__ maskb,
    float* __restrict__ combT)
{
    const int i = blockIdx.x, h = blockIdx.y, j = threadIdx.x;
    __shared__ float red[128];
    __shared__ int boolFlag;

    {   // inline dtype sniff
        int cnt = 0;
        const int base = j * 16;
#pragma unroll
        for (int t = 0; t < 16; ++t) cnt += (maskb[base + t] != 0);
        red[j] = (float)cnt;
        __syncthreads();
        for (int s = 64; s > 0; s >>= 1) {
            if (j < s) red[j] += red[j + s];
            __syncthreads();
        }
        if (j == 0) boolFlag = (red[0] > 200.0f) ? 1 : 0;
        __syncthreads();
    }

    float dv = dir_vec[h * C_ + j];
    red[j] = dv * dv;
    __syncthreads();
    for (int s = 64; s > 0; s >>= 1) {
        if (j < s) red[j] += red[j + s];
        __syncthreads();
    }
    const float nrm = fmaxf(sqrtf(red[0]), 1e-12f);
    __syncthreads();

    const float dvn_j = dir_vec[h * C_ + j] / nrm;
    const float dvn_i = dir_vec[h * C_ + i] / nrm;
    const float third = 1.0f / 3.0f;
    const float dm_ij = (disp[(i * C_ + j) * 3 + 0] + disp[(i * C_ + j) * 3 + 1] +
                         disp[(i * C_ + j) * 3 + 2]) * third;
    const float dm_ji = (disp[(j * C_ + i) * 3 + 0] + disp[(j * C_ + i) * 3 + 1] +
                         disp[(j * C_ + i) * 3 + 2]) * third;
    const float db = 0.5f * (dm_ij * dvn_j - dm_ji * dvn_i);

    red[j] = db;
    __syncthreads();
    for (int s = 64; s > 0; s >>= 1) {
        if (j < s) red[j] += red[j + s];
        __syncthreads();
    }
    const float rowmean = red[0] * (1.0f / 128.0f);

    const bool mk = boolFlag ? (maskb[i * C_ + j] != 0)
                             : (((const int*)maskb)[i * C_ + j] != 0);
    combT[((size_t)h * C_ + j) * C_ + i] =
        mk ? (attn_bias[i * C_ + j] + db - rowmean) : -INFINITY;
}

// ---------------------------------------------------------------------------
// Fused weight + x split. Flat grid 1536 x 256 thr:
//   id < 512 : wsplit — 4 W matrices [E][E] fp32 -> hi/lo bf16, stacked.
//   id >= 512: xsplit — x [B][E][C] fp32 -> xT hi/lo bf16 [B][C][E].
// ---------------------------------------------------------------------------
__global__ __launch_bounds__(256) void split_kernel(
    const float* __restrict__ w0, const float* __restrict__ w1,
    const float* __restrict__ w2, const float* __restrict__ w3,
    const float* __restrict__ x,
    ushort* __restrict__ wh, ushort* __restrict__ wl,
    ushort* __restrict__ xh, ushort* __restrict__ xl)
{
    __shared__ float ts[64][132];
    const int id = blockIdx.x;
    const int tid = threadIdx.x;

    if (id < 512) {
        const int s = id >> 7;
        const float* __restrict__ w = (s == 0) ? w0 : (s == 1) ? w1
                                    : (s == 2) ? w2 : w3;
        const size_t base = (size_t)s * E_ * E_;
        const size_t i0 = ((size_t)(id & 127) * 256 + tid) * 8;
        const float4 f0 = *(const float4*)&w[i0];
        const float4 f1 = *(const float4*)&w[i0 + 4];
        const float ff[8] = {f0.x, f0.y, f0.z, f0.w, f1.x, f1.y, f1.z, f1.w};
        union { ushort u[8]; uint4 v; } hu, lu;
#pragma unroll
        for (int j = 0; j < 8; ++j) split_bf(ff[j], hu.u[j], lu.u[j]);
        *(uint4*)&wh[base + i0] = hu.v;
        *(uint4*)&wl[base + i0] = lu.v;
        return;
    }

    const int fid = id - 512;
    const int b = fid >> 3, e0 = (fid & 7) * 64;
    const float* __restrict__ xb = x + ((size_t)b * E_ + e0) * C_;
#pragma unroll
    for (int r = 0; r < 8; ++r) {
        const int idx = tid + r * 256;
        const int e = idx >> 5, c4 = idx & 31;
        *(float4*)&ts[e][c4 * 4] = *(const float4*)&xb[(size_t)e * C_ + c4 * 4];
    }
    __syncthreads();
    const int lc = tid >> 3;
    const int l8 = (tid & 7) * 8;
#pragma unroll
    for (int p = 0; p < 4; ++p) {
        const int c = p * 32 + lc;
        union { ushort u[8]; uint4 v; } hu, lu;
#pragma unroll
        for (int j = 0; j < 8; ++j) split_bf(ts[l8 + j][c], hu.u[j], lu.u[j]);
        const size_t rb = ((size_t)b * C_ + c) * E_ + e0 + l8;
        *(uint4*)&xh[rb] = hu.v;
        *(uint4*)&xl[rb] = lu.v;
    }
}

// ---------------------------------------------------------------------------
// Split-bf16 MFMA GEMM (r10/r11/r13 verified structure: 128x128, BK=64,
// 4 waves, XOR-swizzled LDS, b-grouped XCD remap). v (z==2) 2-term split.
// MODE 0: z=0 q trans split / z=1 k trans split / z=2 v natural hi-only.
// MODE 1: out-proj fp32+selu (always 3-term).
// ---------------------------------------------------------------------------
template<int MODE>
__global__ __launch_bounds__(256, 2) void gemm_kernel(
    const ushort* __restrict__ Wh0, const ushort* __restrict__ Wh1,
    const ushort* __restrict__ Wh2, const ushort* __restrict__ Wl0,
    const ushort* __restrict__ Wl1, const ushort* __restrict__ Wl2,
    const ushort* __restrict__ Bh, const ushort* __restrict__ Bl,
    ushort* __restrict__ qh, ushort* __restrict__ ql,
    ushort* __restrict__ kh, ushort* __restrict__ kl,
    ushort* __restrict__ vhp, float* __restrict__ fout)
{
    // b-grouped XCD remap
    const int d = blockIdx.x;
    const int xr = d & 7, slot = d >> 3;
    const int G = (MODE == 0) ? 12 : 4;
    const int b = xr + 8 * (slot / G);
    const int u = slot % G;
    const int z = (MODE == 0) ? (u >> 2) : 0;
    const int o0 = (MODE == 0) ? ((u & 3) * 128) : (u * 128);

    const ushort* __restrict__ wh = (z == 0) ? Wh0 : (z == 1) ? Wh1 : Wh2;
    const ushort* __restrict__ wl = (z == 0) ? Wl0 : (z == 1) ? Wl1 : Wl2;
    const bool trans = (MODE == 0) && (z < 2);
    const bool full3 = (MODE == 1) || (z != 2);   // v: 2-term split

    __shared__ ushort sm[4 * 8192];   // Whi | Wlo | Xhi | Xlo, each [128][64]

    const int tid = threadIdx.x;
    const int wid = tid >> 6, lane = tid & 63;
    const int wr64 = (wid >> 1) * 64, wc64 = (wid & 1) * 64;
    const int w4 = wid * 4;
    const int srow = lane >> 3;                       // row&7 within inst block
    const size_t gco = (size_t)((lane & 7) ^ srow) * 16;   // pre-swizzled source

    const char* __restrict__ bhp = (const char*)(Bh + (size_t)b * C_ * E_);
    const char* __restrict__ blp = (const char*)(Bl + (size_t)b * C_ * E_);
    const char* __restrict__ whp = (const char*)wh;
    const char* __restrict__ wlp = (const char*)wl;

    const char* __restrict__ smb = (const char*)sm;
    const int aoffB = trans ? 32768 : 0;     // A-frags from X tile if trans
    const int boffB = trans ? 0 : 32768;

    f32x4 acc[4][4];
#pragma unroll
    for (int m = 0; m < 4; ++m)
#pragma unroll
        for (int n = 0; n < 4; ++n) acc[m][n] = (f32x4)0.0f;

    const int l15 = lane & 15;

    for (int k0 = 0; k0 < E_; k0 += 64) {
#pragma unroll
        for (int t = 0; t < 4; ++t) {
            const int inst = w4 + t;
            const int r = inst * 8 + srow;
            const size_t arow = ((size_t)(o0 + r) * E_ + k0) * 2 + gco;
            const size_t brow = ((size_t)r * E_ + k0) * 2 + gco;
            gll16(whp + arow, &sm[inst * 512]);
            if (full3) gll16(wlp + arow, &sm[8192 + inst * 512]);
            gll16(bhp + brow, &sm[16384 + inst * 512]);
            gll16(blp + brow, &sm[24576 + inst * 512]);
        }
        __syncthreads();
#pragma unroll
        for (int kk = 0; kk < 2; ++kk) {
            const int kbyte = kk * 64 + (lane >> 4) * 16;
            bf16x8 ah[4], al[4], bh4[4], bl4[4];
#pragma unroll
            for (int m = 0; m < 4; ++m) {
                const int r = wr64 + m * 16 + l15;
                const int byt = r * 128 + (kbyte ^ ((r & 7) << 4));
                ah[m] = *(const bf16x8*)(smb + aoffB + byt);
                if (full3) al[m] = *(const bf16x8*)(smb + aoffB + 16384 + byt);
            }
#pragma unroll
            for (int n = 0; n < 4; ++n) {
                const int c = wc64 + n * 16 + l15;
                const int byt = c * 128 + (kbyte ^ ((c & 7) << 4));
                bh4[n] = *(const bf16x8*)(smb + boffB + byt);
                bl4[n] = *(const bf16x8*)(smb + boffB + 16384 + byt);
            }
#pragma unroll
            for (int m = 0; m < 4; ++m)
#pragma unroll
                for (int n = 0; n < 4; ++n)
                    acc[m][n] = __builtin_amdgcn_mfma_f32_16x16x32_bf16(
                        ah[m], bh4[n], acc[m][n], 0, 0, 0);
#pragma unroll
            for (int m = 0; m < 4; ++m)
#pragma unroll
                for (int n = 0; n < 4; ++n)
                    acc[m][n] = __builtin_amdgcn_mfma_f32_16x16x32_bf16(
                        ah[m], bl4[n], acc[m][n], 0, 0, 0);
            if (full3) {
#pragma unroll
                for (int m = 0; m < 4; ++m)
#pragma unroll
                    for (int n = 0; n < 4; ++n)
                        acc[m][n] = __builtin_amdgcn_mfma_f32_16x16x32_bf16(
                            al[m], bh4[n], acc[m][n], 0, 0, 0);
            }
        }
        __syncthreads();
    }

    const int lr = (lane >> 4) * 4, lc = lane & 15;   // C/D: col=lane&15
    if (MODE == 1) {
        float* __restrict__ outb = fout + (size_t)b * E_ * C_;
#pragma unroll
        for (int m = 0; m < 4; ++m)
#pragma unroll
            for (int n = 0; n < 4; ++n) {
                float* po = outb + (size_t)(o0 + wr64 + m * 16 + lr) * C_ +
                            wc64 + n * 16 + lc;
                const f32x4 a = acc[m][n];
#pragma unroll
                for (int j = 0; j < 4; ++j) po[(size_t)j * C_] = selu_f(a[j]);
            }
    } else if (z == 2) {
        // v: natural [b][E][C], hi only
#pragma unroll
        for (int m = 0; m < 4; ++m)
#pragma unroll
            for (int n = 0; n < 4; ++n) {
                const f32x4 a = acc[m][n];
#pragma unroll
                for (int j = 0; j < 4; ++j) {
                    const size_t idx = ((size_t)b * E_ + o0 + wr64 + m * 16 + lr + j) * C_ +
                                       wc64 + n * 16 + lc;
                    vhp[idx] = f2bf(selu_f(a[j]));
                }
            }
    } else {
        // q/k: transposed [b][c][E], split hi/lo. rows=c, cols=o.
        ushort* __restrict__ th = z ? kh : qh;
        ushort* __restrict__ tl = z ? kl : ql;
#pragma unroll
        for (int m = 0; m < 4; ++m)
#pragma unroll
            for (int n = 0; n < 4; ++n) {
                const f32x4 a = acc[m][n];
#pragma unroll
                for (int j = 0; j < 4; ++j) {
                    const int c = wr64 + m * 16 + lr + j;
                    const int o = o0 + wc64 + n * 16 + lc;
                    const size_t idx = ((size_t)b * C_ + c) * E_ + o;
                    ushort hi, lo;
                    split_bf(selu_f(a[j]), hi, lo);
                    th[idx] = hi;
                    tl[idx] = lo;
                }
            }
    }
}

// ---------------------------------------------------------------------------
// MFMA attention, one block (4 waves) per (b,h), b-grouped XCD remap.
// 80 KB LDS -> 2 blocks/CU. (verified passing)
// ---------------------------------------------------------------------------
__global__ __launch_bounds__(256, 2) void attn_mfma_kernel(
    const ushort* __restrict__ qTh, const ushort* __restrict__ qTl,
    const ushort* __restrict__ kTh, const ushort* __restrict__ kTl,
    const ushort* __restrict__ vh,  const float* __restrict__ combT,
    ushort* __restrict__ aTh, ushort* __restrict__ aTl)
{
    const int dd_ = blockIdx.x;
    const int b = (dd_ & 7) + 8 * ((dd_ >> 3) >> 3);
    const int h = (dd_ >> 3) & 7;
    __shared__ ushort lds[40960];
    ushort* sQh = lds;
    ushort* sQl = lds + 8192;
    ushort* sKh = lds + 16384;
    ushort* sKl = lds + 24576;
    ushort* sV  = lds + 32768;
    ushort* sPh = lds;
    ushort* sPl = lds + 16384;

    const int tid = threadIdx.x, wid = tid >> 6, lane = tid & 63;

    {
        const size_t gq = (size_t)b * C_ * E_ + h * D_;
        const int rsub = lane >> 3, chunk = lane & 7;
#pragma unroll
        for (int t = 0; t < 4; ++t) {
            const int inst = wid * 4 + t;
            const int row = inst * 8 + rsub;
            const size_t goff = (gq + (size_t)row * E_) * 2 +
                                (size_t)(chunk ^ (row & 7)) * 16;
            gll16((const char*)qTh + goff, &sQh[inst * 512]);
            gll16((const char*)qTl + goff, &sQl[inst * 512]);
            gll16((const char*)kTh + goff, &sKh[inst * 512]);
            gll16((const char*)kTl + goff, &sKl[inst * 512]);
        }
        const size_t gv = ((size_t)b * E_ + h * D_) * C_;
        const int vr = lane >> 4, vchunk = lane & 15;
#pragma unroll
        for (int t = 0; t < 4; ++t) {
            const int inst = wid * 4 + t;
            const int row = inst * 4 + vr;
            const size_t goff = (gv + (size_t)row * C_) * 2 +
                                (size_t)(vchunk ^ (row & 7)) * 16;
            gll16((const char*)vh + goff, &sV[inst * 512]);
        }
    }
    __syncthreads();

    const int i0 = wid * 32;
    const int l15 = lane & 15;

    f32x4 acc[2][8];
#pragma unroll
    for (int m = 0; m < 2; ++m)
#pragma unroll
        for (int n = 0; n < 8; ++n) acc[m][n] = (f32x4)0.0f;

#pragma unroll
    for (int kk = 0; kk < 2; ++kk) {
        const int kbyte = kk * 64 + (lane >> 4) * 16;
        bf16x8 qhf[2], qlf[2];
#pragma unroll
        for (int m = 0; m < 2; ++m) {
            const int r = i0 + m * 16 + l15;
            const int byt = r * 128 + (kbyte ^ ((r & 7) << 4));
            qhf[m] = *(const bf16x8*)((const char*)sQh + byt);
            qlf[m] = *(const bf16x8*)((const char*)sQl + byt);
        }
#pragma unroll
        for (int n = 0; n < 8; ++n) {
            const int r = n * 16 + l15;
            const int byt = r * 128 + (kbyte ^ ((r & 7) << 4));
            const bf16x8 khf = *(const bf16x8*)((const char*)sKh + byt);
            const bf16x8 klf = *(const bf16x8*)((const char*)sKl + byt);
#pragma unroll
            for (int m = 0; m < 2; ++m) {
                acc[m][n] = __builtin_amdgcn_mfma_f32_16x16x32_bf16(
                    qhf[m], khf, acc[m][n], 0, 0, 0);
                acc[m][n] = __builtin_amdgcn_mfma_f32_16x16x32_bf16(
                    qhf[m], klf, acc[m][n], 0, 0, 0);
                acc[m][n] = __builtin_amdgcn_mfma_f32_16x16x32_bf16(
                    qlf[m], khf, acc[m][n], 0, 0, 0);
            }
        }
    }

#pragma unroll
    for (int m = 0; m < 2; ++m)
#pragma unroll
        for (int n = 0; n < 8; ++n) {
            const int jcol = n * 16 + l15;
            const float4 cb = *(const float4*)&combT[
                ((size_t)h * C_ + jcol) * C_ + i0 + m * 16 + (lane >> 4) * 4];
            acc[m][n][0] = fmaf(acc[m][n][0], 0.125f, cb.x);
            acc[m][n][1] = fmaf(acc[m][n][1], 0.125f, cb.y);
            acc[m][n][2] = fmaf(acc[m][n][2], 0.125f, cb.z);
            acc[m][n][3] = fmaf(acc[m][n][3], 0.125f, cb.w);
        }

#pragma unroll
    for (int m = 0; m < 2; ++m)
#pragma unroll
        for (int jj = 0; jj < 4; ++jj) {
            float mx = -INFINITY;
#pragma unroll
            for (int n = 0; n < 8; ++n) mx = fmaxf(mx, acc[m][n][jj]);
#pragma unroll
            for (int off = 1; off < 16; off <<= 1)
                mx = fmaxf(mx, __shfl_xor(mx, off));
            float sum = 0.0f;
#pragma unroll
            for (int n = 0; n < 8; ++n) {
                const float e = __expf(acc[m][n][jj] - mx);
                acc[m][n][jj] = e;
                sum += e;
            }
#pragma unroll
            for (int off = 1; off < 16; off <<= 1) sum += __shfl_xor(sum, off);
            const float inv = 1.0f / sum;
#pragma unroll
            for (int n = 0; n < 8; ++n) acc[m][n][jj] *= inv;
        }

    __syncthreads();
#pragma unroll
    for (int m = 0; m < 2; ++m)
#pragma unroll
        for (int n = 0; n < 8; ++n)
#pragma unroll
            for (int jj = 0; jj < 4; ++jj) {
                const int i = i0 + m * 16 + (lane >> 4) * 4 + jj;
                const int col = n * 16 + l15;
                const int byt = i * 256 + ((col * 2) ^ ((i & 7) << 4));
                ushort hi, lo;
                split_bf(acc[m][n][jj], hi, lo);
                *(ushort*)((char*)sPh + byt) = hi;
                *(ushort*)((char*)sPl + byt) = lo;
            }
    __syncthreads();

    f32x4 acc2[2][4];
#pragma unroll
    for (int m = 0; m < 2; ++m)
#pragma unroll
        for (int n = 0; n < 4; ++n) acc2[m][n] = (f32x4)0.0f;

#pragma unroll
    for (int ks = 0; ks < 4; ++ks) {
        const int kbyte = ks * 64 + (lane >> 4) * 16;
        bf16x8 ph[2], pl[2];
#pragma unroll
        for (int m = 0; m < 2; ++m) {
            const int r = i0 + m * 16 + l15;
            const int byt = r * 256 + (kbyte ^ ((r & 7) << 4));
            ph[m] = *(const bf16x8*)((const char*)sPh + byt);
            pl[m] = *(const bf16x8*)((const char*)sPl + byt);
        }
#pragma unroll
        for (int n = 0; n < 4; ++n) {
            const int dcol = n * 16 + l15;
            const int byt = dcol * 256 + (kbyte ^ ((dcol & 7) << 4));
            const bf16x8 vb = *(const bf16x8*)((const char*)sV + byt);
#pragma unroll
            for (int m = 0; m < 2; ++m) {
                acc2[m][n] = __builtin_amdgcn_mfma_f32_16x16x32_bf16(
                    ph[m], vb, acc2[m][n], 0, 0, 0);
                acc2[m][n] = __builtin_amdgcn_mfma_f32_16x16x32_bf16(
                    pl[m], vb, acc2[m][n], 0, 0, 0);
            }
        }
    }

#pragma unroll
    for (int m = 0; m < 2; ++m)
#pragma unroll
        for (int n = 0; n < 4; ++n)
#pragma unroll
            for (int jj = 0; jj < 4; ++jj) {
                const int i = i0 + m * 16 + (lane >> 4) * 4 + jj;
                const int dcol = n * 16 + l15;
                ushort hi, lo;
                split_bf(acc2[m][n][jj], hi, lo);
                const size_t idx = ((size_t)b * C_ + i) * E_ + h * D_ + dcol;
                aTh[idx] = hi;
                aTl[idx] = lo;
            }
}

// ---------------------------------------------------------------------------
extern "C" void kernel_launch(void* const* d_in, const int* in_sizes, int n_in,
                              void* d_out, int out_size, void* d_ws, size_t ws_size,
                              hipStream_t stream) {
    const float* x        = (const float*)d_in[0];
    const float* wq       = (const float*)d_in[1];
    const float* wk       = (const float*)d_in[2];
    const float* wv       = (const float*)d_in[3];
    const float* wo       = (const float*)d_in[4];
    const float* dir_vec  = (const float*)d_in[5];
    const float* attn_b   = (const float*)d_in[6];
    const float* disp     = (const float*)d_in[7];
    const unsigned char* knn = (const unsigned char*)d_in[8];
    float* out = (float*)d_out;

    char* ws = (char*)d_ws;
    size_t off = 0;
    ushort* qTh = (ushort*)(ws + off); off += BEC_ * 2;
    ushort* qTl = (ushort*)(ws + off); off += BEC_ * 2;
    ushort* kTh = (ushort*)(ws + off); off += BEC_ * 2;
    ushort* kTl = (ushort*)(ws + off); off += BEC_ * 2;
    ushort* vbuf = (ushort*)(ws + off); off += BEC_ * 2;
    ushort* xTh = (ushort*)(ws + off); off += BEC_ * 2;   // reused as attnT hi
    ushort* xTl = (ushort*)(ws + off); off += BEC_ * 2;   // reused as attnT lo
    ushort* wh  = (ushort*)(ws + off); off += (size_t)4 * E_ * E_ * 2;
    ushort* wl  = (ushort*)(ws + off); off += (size_t)4 * E_ * E_ * 2;
    float* combT = (float*)(ws + off); off += (size_t)H_ * C_ * C_ * sizeof(float);

    // bias (with inline mask-dtype detect)
    bias_prep_kernel<<<dim3(C_, H_), 128, 0, stream>>>(dir_vec, attn_b, disp,
                                                       knn, combT);
    // fused weight + x split
    split_kernel<<<1536, 256, 0, stream>>>(wq, wk, wv, wo, x, wh, wl, xTh, xTl);

    const size_t WSZ = (size_t)E_ * E_;
    // q (trans), k (trans), v (natural hi, 2-term), b-grouped flat grid
    gemm_kernel<0><<<1536, 256, 0, stream>>>(
        wh, wh + WSZ, wh + 2 * WSZ, wl, wl + WSZ, wl + 2 * WSZ,
        xTh, xTl, qTh, qTl, kTh, kTl, vbuf, nullptr);
    // MFMA attention -> attnT over xT buffers, b-grouped flat grid
    attn_mfma_kernel<<<1024, 256, 0, stream>>>(
        qTh, qTl, kTh, kTl, vbuf, combT, xTh, xTl);
    // output projection -> d_out, b-grouped flat grid
    gemm_kernel<1><<<512, 256, 0, stream>>>(
        wh + 3 * WSZ, wh + 3 * WSZ, wh + 3 * WSZ,
        wl + 3 * WSZ, wl + 3 * WSZ, wl + 3 * WSZ,
        xTh, xTl, nullptr, nullptr, nullptr, nullptr, nullptr, out);
}

// Round 17
// 171.437 us; speedup vs baseline: 1.0724x; 1.0267x over previous
//
#include <hip/hip_runtime.h>
#include <math.h>

#define B_ 128
#define E_ 512
#define C_ 128
#define H_ 8
#define D_ 64
#define BEC_ ((size_t)B_ * E_ * C_)

typedef __attribute__((ext_vector_type(8))) __bf16 bf16x8;
typedef __attribute__((ext_vector_type(4))) float f32x4;

__device__ __forceinline__ ushort f2bf(float f) {
    unsigned u = __float_as_uint(f);
    unsigned r = u + 0x7fffu + ((u >> 16) & 1u);
    return (ushort)(r >> 16);
}
__device__ __forceinline__ float bf2f(ushort h) {
    return __uint_as_float(((unsigned)h) << 16);
}
__device__ __forceinline__ void split_bf(float f, ushort& hi, ushort& lo) {
    hi = f2bf(f);
    lo = f2bf(f - bf2f(hi));
}
__device__ __forceinline__ float selu_f(float x) {
    const float alpha = 1.6732632423543772f;
    const float scale = 1.0507009873554805f;
    return x > 0.0f ? scale * x : scale * alpha * expm1f(x);
}
// async global->LDS, 16B/lane; LDS dest wave-uniform base + lane*16
__device__ __forceinline__ void gll16(const void* g, void* l) {
    __builtin_amdgcn_global_load_lds(
        (const __attribute__((address_space(1))) void*)g,
        (__attribute__((address_space(3))) void*)l, 16, 0, 0);
}

// ---------------------------------------------------------------------------
// Fused prep: one launch does weight-split, x-split, AND bias/combT.
// Flat grid 2048 x 256 thr:
//   id <  512 : wsplit — 4 W matrices [E][E] fp32 -> hi/lo bf16, stacked.
//   id < 1536 : xsplit — x [B][E][C] fp32 -> xT hi/lo bf16 [B][C][E].
//   id >=1536 : bias   — two (i,h) rows per block (sub = tid>>7):
//               combT[h][j][i] = mask ? attn_bias + centered dir bias : -inf.
//               Mask dtype sniff inlined (first 2048 bytes: bool -> 336
//               nonzero, int32 -> 84; threshold 200).
// Branch is blockIdx-uniform, so __syncthreads inside branches is legal.
// ---------------------------------------------------------------------------
__global__ __launch_bounds__(256) void prep_kernel(
    const float* __restrict__ w0, const float* __restrict__ w1,
    const float* __restrict__ w2, const float* __restrict__ w3,
    const float* __restrict__ x,
    const float* __restrict__ dir_vec, const float* __restrict__ attn_bias,
    const float* __restrict__ disp, const unsigned char* __restrict__ maskb,
    ushort* __restrict__ wh, ushort* __restrict__ wl,
    ushort* __restrict__ xh, ushort* __restrict__ xl,
    float* __restrict__ combT)
{
    __shared__ float ts[64][132];
    __shared__ float red2[2][128];
    __shared__ int boolFlag;
    const int id = blockIdx.x;
    const int tid = threadIdx.x;

    if (id >= 1536) {
        // ---- bias path: two (i,h) pairs per block
        const int sub = tid >> 7, j = tid & 127;
        const int p = (id - 1536) * 2 + sub;     // 0..1023
        const int i = p & 127, h = p >> 7;

        {   // dtype sniff over first 2048 bytes (8 B per thread)
            int cnt = 0;
            const int base = tid * 8;
#pragma unroll
            for (int t = 0; t < 8; ++t) cnt += (maskb[base + t] != 0);
            red2[sub][j] = (float)cnt;
            __syncthreads();
            for (int s = 64; s > 0; s >>= 1) {
                if (j < s) red2[sub][j] += red2[sub][j + s];
                __syncthreads();
            }
            if (tid == 0)
                boolFlag = (red2[0][0] + red2[1][0] > 200.0f) ? 1 : 0;
            __syncthreads();
        }

        float dv = dir_vec[h * C_ + j];
        red2[sub][j] = dv * dv;
        __syncthreads();
        for (int s = 64; s > 0; s >>= 1) {
            if (j < s) red2[sub][j] += red2[sub][j + s];
            __syncthreads();
        }
        const float nrm = fmaxf(sqrtf(red2[sub][0]), 1e-12f);
        __syncthreads();

        const float dvn_j = dir_vec[h * C_ + j] / nrm;
        const float dvn_i = dir_vec[h * C_ + i] / nrm;
        const float third = 1.0f / 3.0f;
        const float dm_ij = (disp[(i * C_ + j) * 3 + 0] + disp[(i * C_ + j) * 3 + 1] +
                             disp[(i * C_ + j) * 3 + 2]) * third;
        const float dm_ji = (disp[(j * C_ + i) * 3 + 0] + disp[(j * C_ + i) * 3 + 1] +
                             disp[(j * C_ + i) * 3 + 2]) * third;
        const float db = 0.5f * (dm_ij * dvn_j - dm_ji * dvn_i);

        red2[sub][j] = db;
        __syncthreads();
        for (int s = 64; s > 0; s >>= 1) {
            if (j < s) red2[sub][j] += red2[sub][j + s];
            __syncthreads();
        }
        const float rowmean = red2[sub][0] * (1.0f / 128.0f);

        const bool mk = boolFlag ? (maskb[i * C_ + j] != 0)
                                 : (((const int*)maskb)[i * C_ + j] != 0);
        combT[((size_t)h * C_ + j) * C_ + i] =
            mk ? (attn_bias[i * C_ + j] + db - rowmean) : -INFINITY;
        return;
    }

    if (id < 512) {
        // ---- wsplit path
        const int s = id >> 7;
        const float* __restrict__ w = (s == 0) ? w0 : (s == 1) ? w1
                                    : (s == 2) ? w2 : w3;
        const size_t base = (size_t)s * E_ * E_;
        const size_t i0 = ((size_t)(id & 127) * 256 + tid) * 8;
        const float4 f0 = *(const float4*)&w[i0];
        const float4 f1 = *(const float4*)&w[i0 + 4];
        const float ff[8] = {f0.x, f0.y, f0.z, f0.w, f1.x, f1.y, f1.z, f1.w};
        union { ushort u[8]; uint4 v; } hu, lu;
#pragma unroll
        for (int j = 0; j < 8; ++j) split_bf(ff[j], hu.u[j], lu.u[j]);
        *(uint4*)&wh[base + i0] = hu.v;
        *(uint4*)&wl[base + i0] = lu.v;
        return;
    }

    // ---- xsplit path
    const int fid = id - 512;
    const int b = fid >> 3, e0 = (fid & 7) * 64;
    const float* __restrict__ xb = x + ((size_t)b * E_ + e0) * C_;
#pragma unroll
    for (int r = 0; r < 8; ++r) {
        const int idx = tid + r * 256;
        const int e = idx >> 5, c4 = idx & 31;
        *(float4*)&ts[e][c4 * 4] = *(const float4*)&xb[(size_t)e * C_ + c4 * 4];
    }
    __syncthreads();
    const int lc = tid >> 3;
    const int l8 = (tid & 7) * 8;
#pragma unroll
    for (int p = 0; p < 4; ++p) {
        const int c = p * 32 + lc;
        union { ushort u[8]; uint4 v; } hu, lu;
#pragma unroll
        for (int j = 0; j < 8; ++j) split_bf(ts[l8 + j][c], hu.u[j], lu.u[j]);
        const size_t rb = ((size_t)b * C_ + c) * E_ + e0 + l8;
        *(uint4*)&xh[rb] = hu.v;
        *(uint4*)&xl[rb] = lu.v;
    }
}

// ---------------------------------------------------------------------------
// Split-bf16 MFMA GEMM (r10/r11/r13 verified structure: 128x128, BK=64,
// 4 waves, XOR-swizzled LDS, b-grouped XCD remap). v (z==2) 2-term split.
// MODE 0: z=0 q trans split / z=1 k trans split / z=2 v natural hi-only.
// MODE 1: out-proj fp32+selu (always 3-term).
// ---------------------------------------------------------------------------
template<int MODE>
__global__ __launch_bounds__(256, 2) void gemm_kernel(
    const ushort* __restrict__ Wh0, const ushort* __restrict__ Wh1,
    const ushort* __restrict__ Wh2, const ushort* __restrict__ Wl0,
    const ushort* __restrict__ Wl1, const ushort* __restrict__ Wl2,
    const ushort* __restrict__ Bh, const ushort* __restrict__ Bl,
    ushort* __restrict__ qh, ushort* __restrict__ ql,
    ushort* __restrict__ kh, ushort* __restrict__ kl,
    ushort* __restrict__ vhp, float* __restrict__ fout)
{
    // b-grouped XCD remap
    const int d = blockIdx.x;
    const int xr = d & 7, slot = d >> 3;
    const int G = (MODE == 0) ? 12 : 4;
    const int b = xr + 8 * (slot / G);
    const int u = slot % G;
    const int z = (MODE == 0) ? (u >> 2) : 0;
    const int o0 = (MODE == 0) ? ((u & 3) * 128) : (u * 128);

    const ushort* __restrict__ wh = (z == 0) ? Wh0 : (z == 1) ? Wh1 : Wh2;
    const ushort* __restrict__ wl = (z == 0) ? Wl0 : (z == 1) ? Wl1 : Wl2;
    const bool trans = (MODE == 0) && (z < 2);
    const bool full3 = (MODE == 1) || (z != 2);   // v: 2-term split

    __shared__ ushort sm[4 * 8192];   // Whi | Wlo | Xhi | Xlo, each [128][64]

    const int tid = threadIdx.x;
    const int wid = tid >> 6, lane = tid & 63;
    const int wr64 = (wid >> 1) * 64, wc64 = (wid & 1) * 64;
    const int w4 = wid * 4;
    const int srow = lane >> 3;                       // row&7 within inst block
    const size_t gco = (size_t)((lane & 7) ^ srow) * 16;   // pre-swizzled source

    const char* __restrict__ bhp = (const char*)(Bh + (size_t)b * C_ * E_);
    const char* __restrict__ blp = (const char*)(Bl + (size_t)b * C_ * E_);
    const char* __restrict__ whp = (const char*)wh;
    const char* __restrict__ wlp = (const char*)wl;

    const char* __restrict__ smb = (const char*)sm;
    const int aoffB = trans ? 32768 : 0;     // A-frags from X tile if trans
    const int boffB = trans ? 0 : 32768;

    f32x4 acc[4][4];
#pragma unroll
    for (int m = 0; m < 4; ++m)
#pragma unroll
        for (int n = 0; n < 4; ++n) acc[m][n] = (f32x4)0.0f;

    const int l15 = lane & 15;

    for (int k0 = 0; k0 < E_; k0 += 64) {
#pragma unroll
        for (int t = 0; t < 4; ++t) {
            const int inst = w4 + t;
            const int r = inst * 8 + srow;
            const size_t arow = ((size_t)(o0 + r) * E_ + k0) * 2 + gco;
            const size_t brow = ((size_t)r * E_ + k0) * 2 + gco;
            gll16(whp + arow, &sm[inst * 512]);
            if (full3) gll16(wlp + arow, &sm[8192 + inst * 512]);
            gll16(bhp + brow, &sm[16384 + inst * 512]);
            gll16(blp + brow, &sm[24576 + inst * 512]);
        }
        __syncthreads();
#pragma unroll
        for (int kk = 0; kk < 2; ++kk) {
            const int kbyte = kk * 64 + (lane >> 4) * 16;
            bf16x8 ah[4], al[4], bh4[4], bl4[4];
#pragma unroll
            for (int m = 0; m < 4; ++m) {
                const int r = wr64 + m * 16 + l15;
                const int byt = r * 128 + (kbyte ^ ((r & 7) << 4));
                ah[m] = *(const bf16x8*)(smb + aoffB + byt);
                if (full3) al[m] = *(const bf16x8*)(smb + aoffB + 16384 + byt);
            }
#pragma unroll
            for (int n = 0; n < 4; ++n) {
                const int c = wc64 + n * 16 + l15;
                const int byt = c * 128 + (kbyte ^ ((c & 7) << 4));
                bh4[n] = *(const bf16x8*)(smb + boffB + byt);
                bl4[n] = *(const bf16x8*)(smb + boffB + 16384 + byt);
            }
#pragma unroll
            for (int m = 0; m < 4; ++m)
#pragma unroll
                for (int n = 0; n < 4; ++n)
                    acc[m][n] = __builtin_amdgcn_mfma_f32_16x16x32_bf16(
                        ah[m], bh4[n], acc[m][n], 0, 0, 0);
#pragma unroll
            for (int m = 0; m < 4; ++m)
#pragma unroll
                for (int n = 0; n < 4; ++n)
                    acc[m][n] = __builtin_amdgcn_mfma_f32_16x16x32_bf16(
                        ah[m], bl4[n], acc[m][n], 0, 0, 0);
            if (full3) {
#pragma unroll
                for (int m = 0; m < 4; ++m)
#pragma unroll
                    for (int n = 0; n < 4; ++n)
                        acc[m][n] = __builtin_amdgcn_mfma_f32_16x16x32_bf16(
                            al[m], bh4[n], acc[m][n], 0, 0, 0);
            }
        }
        __syncthreads();
    }

    const int lr = (lane >> 4) * 4, lc = lane & 15;   // C/D: col=lane&15
    if (MODE == 1) {
        float* __restrict__ outb = fout + (size_t)b * E_ * C_;
#pragma unroll
        for (int m = 0; m < 4; ++m)
#pragma unroll
            for (int n = 0; n < 4; ++n) {
                float* po = outb + (size_t)(o0 + wr64 + m * 16 + lr) * C_ +
                            wc64 + n * 16 + lc;
                const f32x4 a = acc[m][n];
#pragma unroll
                for (int j = 0; j < 4; ++j) po[(size_t)j * C_] = selu_f(a[j]);
            }
    } else if (z == 2) {
        // v: natural [b][E][C], hi only
#pragma unroll
        for (int m = 0; m < 4; ++m)
#pragma unroll
            for (int n = 0; n < 4; ++n) {
                const f32x4 a = acc[m][n];
#pragma unroll
                for (int j = 0; j < 4; ++j) {
                    const size_t idx = ((size_t)b * E_ + o0 + wr64 + m * 16 + lr + j) * C_ +
                                       wc64 + n * 16 + lc;
                    vhp[idx] = f2bf(selu_f(a[j]));
                }
            }
    } else {
        // q/k: transposed [b][c][E], split hi/lo. rows=c, cols=o.
        ushort* __restrict__ th = z ? kh : qh;
        ushort* __restrict__ tl = z ? kl : ql;
#pragma unroll
        for (int m = 0; m < 4; ++m)
#pragma unroll
            for (int n = 0; n < 4; ++n) {
                const f32x4 a = acc[m][n];
#pragma unroll
                for (int j = 0; j < 4; ++j) {
                    const int c = wr64 + m * 16 + lr + j;
                    const int o = o0 + wc64 + n * 16 + lc;
                    const size_t idx = ((size_t)b * C_ + c) * E_ + o;
                    ushort hi, lo;
                    split_bf(selu_f(a[j]), hi, lo);
                    th[idx] = hi;
                    tl[idx] = lo;
                }
            }
    }
}

// ---------------------------------------------------------------------------
// MFMA attention, one block (4 waves) per (b,h), b-grouped XCD remap.
// 80 KB LDS -> 2 blocks/CU. (verified passing)
// ---------------------------------------------------------------------------
__global__ __launch_bounds__(256, 2) void attn_mfma_kernel(
    const ushort* __restrict__ qTh, const ushort* __restrict__ qTl,
    const ushort* __restrict__ kTh, const ushort* __restrict__ kTl,
    const ushort* __restrict__ vh,  const float* __restrict__ combT,
    ushort* __restrict__ aTh, ushort* __restrict__ aTl)
{
    const int dd_ = blockIdx.x;
    const int b = (dd_ & 7) + 8 * ((dd_ >> 3) >> 3);
    const int h = (dd_ >> 3) & 7;
    __shared__ ushort lds[40960];
    ushort* sQh = lds;
    ushort* sQl = lds + 8192;
    ushort* sKh = lds + 16384;
    ushort* sKl = lds + 24576;
    ushort* sV  = lds + 32768;
    ushort* sPh = lds;
    ushort* sPl = lds + 16384;

    const int tid = threadIdx.x, wid = tid >> 6, lane = tid & 63;

    {
        const size_t gq = (size_t)b * C_ * E_ + h * D_;
        const int rsub = lane >> 3, chunk = lane & 7;
#pragma unroll
        for (int t = 0; t < 4; ++t) {
            const int inst = wid * 4 + t;
            const int row = inst * 8 + rsub;
            const size_t goff = (gq + (size_t)row * E_) * 2 +
                                (size_t)(chunk ^ (row & 7)) * 16;
            gll16((const char*)qTh + goff, &sQh[inst * 512]);
            gll16((const char*)qTl + goff, &sQl[inst * 512]);
            gll16((const char*)kTh + goff, &sKh[inst * 512]);
            gll16((const char*)kTl + goff, &sKl[inst * 512]);
        }
        const size_t gv = ((size_t)b * E_ + h * D_) * C_;
        const int vr = lane >> 4, vchunk = lane & 15;
#pragma unroll
        for (int t = 0; t < 4; ++t) {
            const int inst = wid * 4 + t;
            const int row = inst * 4 + vr;
            const size_t goff = (gv + (size_t)row * C_) * 2 +
                                (size_t)(vchunk ^ (row & 7)) * 16;
            gll16((const char*)vh + goff, &sV[inst * 512]);
        }
    }
    __syncthreads();

    const int i0 = wid * 32;
    const int l15 = lane & 15;

    f32x4 acc[2][8];
#pragma unroll
    for (int m = 0; m < 2; ++m)
#pragma unroll
        for (int n = 0; n < 8; ++n) acc[m][n] = (f32x4)0.0f;

#pragma unroll
    for (int kk = 0; kk < 2; ++kk) {
        const int kbyte = kk * 64 + (lane >> 4) * 16;
        bf16x8 qhf[2], qlf[2];
#pragma unroll
        for (int m = 0; m < 2; ++m) {
            const int r = i0 + m * 16 + l15;
            const int byt = r * 128 + (kbyte ^ ((r & 7) << 4));
            qhf[m] = *(const bf16x8*)((const char*)sQh + byt);
            qlf[m] = *(const bf16x8*)((const char*)sQl + byt);
        }
#pragma unroll
        for (int n = 0; n < 8; ++n) {
            const int r = n * 16 + l15;
            const int byt = r * 128 + (kbyte ^ ((r & 7) << 4));
            const bf16x8 khf = *(const bf16x8*)((const char*)sKh + byt);
            const bf16x8 klf = *(const bf16x8*)((const char*)sKl + byt);
#pragma unroll
            for (int m = 0; m < 2; ++m) {
                acc[m][n] = __builtin_amdgcn_mfma_f32_16x16x32_bf16(
                    qhf[m], khf, acc[m][n], 0, 0, 0);
                acc[m][n] = __builtin_amdgcn_mfma_f32_16x16x32_bf16(
                    qhf[m], klf, acc[m][n], 0, 0, 0);
                acc[m][n] = __builtin_amdgcn_mfma_f32_16x16x32_bf16(
                    qlf[m], khf, acc[m][n], 0, 0, 0);
            }
        }
    }

#pragma unroll
    for (int m = 0; m < 2; ++m)
#pragma unroll
        for (int n = 0; n < 8; ++n) {
            const int jcol = n * 16 + l15;
            const float4 cb = *(const float4*)&combT[
                ((size_t)h * C_ + jcol) * C_ + i0 + m * 16 + (lane >> 4) * 4];
            acc[m][n][0] = fmaf(acc[m][n][0], 0.125f, cb.x);
            acc[m][n][1] = fmaf(acc[m][n][1], 0.125f, cb.y);
            acc[m][n][2] = fmaf(acc[m][n][2], 0.125f, cb.z);
            acc[m][n][3] = fmaf(acc[m][n][3], 0.125f, cb.w);
        }

#pragma unroll
    for (int m = 0; m < 2; ++m)
#pragma unroll
        for (int jj = 0; jj < 4; ++jj) {
            float mx = -INFINITY;
#pragma unroll
            for (int n = 0; n < 8; ++n) mx = fmaxf(mx, acc[m][n][jj]);
#pragma unroll
            for (int off = 1; off < 16; off <<= 1)
                mx = fmaxf(mx, __shfl_xor(mx, off));
            float sum = 0.0f;
#pragma unroll
            for (int n = 0; n < 8; ++n) {
                const float e = __expf(acc[m][n][jj] - mx);
                acc[m][n][jj] = e;
                sum += e;
            }
#pragma unroll
            for (int off = 1; off < 16; off <<= 1) sum += __shfl_xor(sum, off);
            const float inv = 1.0f / sum;
#pragma unroll
            for (int n = 0; n < 8; ++n) acc[m][n][jj] *= inv;
        }

    __syncthreads();
#pragma unroll
    for (int m = 0; m < 2; ++m)
#pragma unroll
        for (int n = 0; n < 8; ++n)
#pragma unroll
            for (int jj = 0; jj < 4; ++jj) {
                const int i = i0 + m * 16 + (lane >> 4) * 4 + jj;
                const int col = n * 16 + l15;
                const int byt = i * 256 + ((col * 2) ^ ((i & 7) << 4));
                ushort hi, lo;
                split_bf(acc[m][n][jj], hi, lo);
                *(ushort*)((char*)sPh + byt) = hi;
                *(ushort*)((char*)sPl + byt) = lo;
            }
    __syncthreads();

    f32x4 acc2[2][4];
#pragma unroll
    for (int m = 0; m < 2; ++m)
#pragma unroll
        for (int n = 0; n < 4; ++n) acc2[m][n] = (f32x4)0.0f;

#pragma unroll
    for (int ks = 0; ks < 4; ++ks) {
        const int kbyte = ks * 64 + (lane >> 4) * 16;
        bf16x8 ph[2], pl[2];
#pragma unroll
        for (int m = 0; m < 2; ++m) {
            const int r = i0 + m * 16 + l15;
            const int byt = r * 256 + (kbyte ^ ((r & 7) << 4));
            ph[m] = *(const bf16x8*)((const char*)sPh + byt);
            pl[m] = *(const bf16x8*)((const char*)sPl + byt);
        }
#pragma unroll
        for (int n = 0; n < 4; ++n) {
            const int dcol = n * 16 + l15;
            const int byt = dcol * 256 + (kbyte ^ ((dcol & 7) << 4));
            const bf16x8 vb = *(const bf16x8*)((const char*)sV + byt);
#pragma unroll
            for (int m = 0; m < 2; ++m) {
                acc2[m][n] = __builtin_amdgcn_mfma_f32_16x16x32_bf16(
                    ph[m], vb, acc2[m][n], 0, 0, 0);
                acc2[m][n] = __builtin_amdgcn_mfma_f32_16x16x32_bf16(
                    pl[m], vb, acc2[m][n], 0, 0, 0);
            }
        }
    }

#pragma unroll
    for (int m = 0; m < 2; ++m)
#pragma unroll
        for (int n = 0; n < 4; ++n)
#pragma unroll
            for (int jj = 0; jj < 4; ++jj) {
                const int i = i0 + m * 16 + (lane >> 4) * 4 + jj;
                const int dcol = n * 16 + l15;
                ushort hi, lo;
                split_bf(acc2[m][n][jj], hi, lo);
                const size_t idx = ((size_t)b * C_ + i) * E_ + h * D_ + dcol;
                aTh[idx] = hi;
                aTl[idx] = lo;
            }
}

// ---------------------------------------------------------------------------
extern "C" void kernel_launch(void* const* d_in, const int* in_sizes, int n_in,
                              void* d_out, int out_size, void* d_ws, size_t ws_size,
                              hipStream_t stream) {
    const float* x        = (const float*)d_in[0];
    const float* wq       = (const float*)d_in[1];
    const float* wk       = (const float*)d_in[2];
    const float* wv       = (const float*)d_in[3];
    const float* wo       = (const float*)d_in[4];
    const float* dir_vec  = (const float*)d_in[5];
    const float* attn_b   = (const float*)d_in[6];
    const float* disp     = (const float*)d_in[7];
    const unsigned char* knn = (const unsigned char*)d_in[8];
    float* out = (float*)d_out;

    char* ws = (char*)d_ws;
    size_t off = 0;
    ushort* qTh = (ushort*)(ws + off); off += BEC_ * 2;
    ushort* qTl = (ushort*)(ws + off); off += BEC_ * 2;
    ushort* kTh = (ushort*)(ws + off); off += BEC_ * 2;
    ushort* kTl = (ushort*)(ws + off); off += BEC_ * 2;
    ushort* vbuf = (ushort*)(ws + off); off += BEC_ * 2;
    ushort* xTh = (ushort*)(ws + off); off += BEC_ * 2;   // reused as attnT hi
    ushort* xTl = (ushort*)(ws + off); off += BEC_ * 2;   // reused as attnT lo
    ushort* wh  = (ushort*)(ws + off); off += (size_t)4 * E_ * E_ * 2;
    ushort* wl  = (ushort*)(ws + off); off += (size_t)4 * E_ * E_ * 2;
    float* combT = (float*)(ws + off); off += (size_t)H_ * C_ * C_ * sizeof(float);

    // fused prep: weight-split + x-split + bias/combT in ONE launch
    prep_kernel<<<2048, 256, 0, stream>>>(wq, wk, wv, wo, x,
                                          dir_vec, attn_b, disp, knn,
                                          wh, wl, xTh, xTl, combT);

    const size_t WSZ = (size_t)E_ * E_;
    // q (trans), k (trans), v (natural hi, 2-term), b-grouped flat grid
    gemm_kernel<0><<<1536, 256, 0, stream>>>(
        wh, wh + WSZ, wh + 2 * WSZ, wl, wl + WSZ, wl + 2 * WSZ,
        xTh, xTl, qTh, qTl, kTh, kTl, vbuf, nullptr);
    // MFMA attention -> attnT over xT buffers, b-grouped flat grid
    attn_mfma_kernel<<<1024, 256, 0, stream>>>(
        qTh, qTl, kTh, kTl, vbuf, combT, xTh, xTl);
    // output projection -> d_out, b-grouped flat grid
    gemm_kernel<1><<<512, 256, 0, stream>>>(
        wh + 3 * WSZ, wh + 3 * WSZ, wh + 3 * WSZ,
        wl + 3 * WSZ, wl + 3 * WSZ, wl + 3 * WSZ,
        xTh, xTl, nullptr, nullptr, nullptr, nullptr, nullptr, out);
}